// Round 11
// baseline (99.275 us; speedup 1.0000x reference)
//
#include <hip/hip_runtime.h>
#include <stdint.h>

#define NIN 1024
#define NMID 256
#define NOUT 64
#define BM 64
#define BK 32
#define NSTEP 32

typedef __attribute__((ext_vector_type(8))) short bf16x8;
typedef __attribute__((ext_vector_type(4))) float fx4;
typedef __attribute__((ext_vector_type(16))) float f32x16;
typedef __attribute__((ext_vector_type(4))) uint32_t u32x4;

#define XBUF 8192        // one x tile: 64 rows x 128B (fp32), 8-chunk XOR swz

union FragU { bf16x8 v; uint32_t u[4]; };

static __device__ __forceinline__ uint32_t cvtpk(float lo, float hi) {
  uint32_t r;
  asm("v_cvt_pk_bf16_f32 %0, %1, %2" : "=v"(r) : "v"(lo), "v"(hi));
  return r;
}
static __device__ __forceinline__ void gload16(const void* g, void* l) {
  __builtin_amdgcn_global_load_lds(
      (const __attribute__((address_space(1))) uint32_t*)g,
      (__attribute__((address_space(3))) uint32_t*)l, 16, 0, 0);
}

#define SBAR()   __builtin_amdgcn_s_barrier()
#define SFENCE() __builtin_amdgcn_sched_barrier(0)

// ---- kernel 1: W1,W2 -> MFMA-fragment-ready bf16 layouts ----
// w1f chunk idx = c*4096 + kb*32 + r  (c=n>>5 of 8, kb=k>>3 of 128, r=n&31)
// w2f chunk idx = c*1024 + kb*32 + r  (c=n>>5 of 2, kb=k>>3 of 32,  r=n&31)
__global__ __launch_bounds__(256) void cvt_weights(
    const float* __restrict__ W1, const float* __restrict__ W2,
    unsigned short* __restrict__ w1f, unsigned short* __restrict__ w2f) {
  int gid = blockIdx.x * 256 + threadIdx.x;
  if (gid < 32768) {
    int r = gid & 31;
    int kb = (gid >> 5) & 127;
    int c = gid >> 12;
    const float* s = W1 + (size_t)(c * 32 + r) * NIN + kb * 8;
    fx4 v0 = *(const fx4*)s;
    fx4 v1 = *(const fx4*)(s + 4);
    u32x4 o = {cvtpk(v0.x, v0.y), cvtpk(v0.z, v0.w),
               cvtpk(v1.x, v1.y), cvtpk(v1.z, v1.w)};
    *(u32x4*)(w1f + (size_t)gid * 8) = o;
  } else {
    int g2 = gid - 32768;
    if (g2 < 2048) {
      int r = g2 & 31;
      int kb = (g2 >> 5) & 31;
      int c = g2 >> 10;
      const float* s = W2 + (size_t)(c * 32 + r) * NMID + kb * 8;
      fx4 v0 = *(const fx4*)s;
      fx4 v1 = *(const fx4*)(s + 4);
      u32x4 o = {cvtpk(v0.x, v0.y), cvtpk(v0.z, v0.w),
                 cvtpk(v1.x, v1.y), cvtpk(v1.z, v1.w)};
      *(u32x4*)(w2f + (size_t)g2 * 8) = o;
    }
  }
}

// ---- shared layer-1 K-loop body (R8 structure, tail-race fixed) ----
// Produces acc[2][2] and leaves the bias+relu'd h tile in LDS [64][512B],
// chunk-XOR j^(row&31). Used by gemm1 and the fused fallback.
#define L1_PROLOG_AND_LOOP()                                                  \
  uint32_t xsrc[2], xdst[2];                                                  \
  _Pragma("unroll") for (int i = 0; i < 2; ++i) {                             \
    uint32_t o = (uint32_t)(i * 4096 + tid * 16);                             \
    uint32_t r = o >> 7;                                                      \
    uint32_t pcn = (o >> 4) & 7u;                                             \
    uint32_t j = pcn ^ (r & 7u);                                              \
    xsrc[i] = (uint32_t)(row0 + (int)r) * NIN + j * 4u;                       \
    xdst[i] = o;                                                              \
  }                                                                           \
  f32x16 acc[2][2];                                                           \
  _Pragma("unroll") for (int mt = 0; mt < 2; ++mt)                            \
    _Pragma("unroll") for (int nt = 0; nt < 2; ++nt)                          \
      _Pragma("unroll") for (int q = 0; q < 16; ++q) acc[mt][nt][q] = 0.f;    \
  const char* wbase0 =                                                        \
      (const char*)(w1f + ((size_t)(wn * 2 + 0) * 4096 + l31) * 8) + lh * 512;\
  const char* wbase1 =                                                        \
      (const char*)(w1f + ((size_t)(wn * 2 + 1) * 4096 + l31) * 8) + lh * 512;\
  const uint32_t arx = (uint32_t)(l31 & 7);                                   \
  const uint32_t ar0 = (uint32_t)(l31) * 128u;                                \
  const uint32_t ar1 = (uint32_t)(32 + l31) * 128u;                           \
  XSTAGE(0, 0);                                                               \
  XSTAGE(1, BK);                                                              \
  int b3 = 0;                                                                 \
  for (int t = 0; t < NSTEP; ++t) {                                           \
    if (t < NSTEP - 1) { asm volatile("s_waitcnt vmcnt(2)" ::: "memory"); }   \
    else               { asm volatile("s_waitcnt vmcnt(0)" ::: "memory"); }   \
    SBAR();                                                                   \
    SFENCE();                                                                 \
    const char* xb = smem + b3 * XBUF;                                        \
    const int tb = t * 2048;                                                  \
    bf16x8 bfr[2][2];                                                         \
    _Pragma("unroll") for (int kf = 0; kf < 2; ++kf) {                        \
      bfr[0][kf] = *(const bf16x8*)(wbase0 + tb + kf * 1024);                 \
      bfr[1][kf] = *(const bf16x8*)(wbase1 + tb + kf * 1024);                 \
    }                                                                         \
    if (t < NSTEP - 2) {                                                      \
      int nb = b3 + 2; if (nb >= 3) nb -= 3;                                  \
      XSTAGE(nb, (t + 2) * BK);                                               \
    }                                                                         \
    _Pragma("unroll") for (int kf = 0; kf < 2; ++kf) {                        \
      uint32_t j0 = (uint32_t)(kf * 4 + lh * 2);                              \
      fx4 va = *(const fx4*)(xb + ar0 + ((j0 ^ arx) << 4));                   \
      fx4 vb = *(const fx4*)(xb + ar0 + (((j0 + 1) ^ arx) << 4));             \
      fx4 vc = *(const fx4*)(xb + ar1 + ((j0 ^ arx) << 4));                   \
      fx4 vd = *(const fx4*)(xb + ar1 + (((j0 + 1) ^ arx) << 4));             \
      FragU f, g;                                                             \
      f.u[0] = cvtpk(va.x, va.y); f.u[1] = cvtpk(va.z, va.w);                 \
      f.u[2] = cvtpk(vb.x, vb.y); f.u[3] = cvtpk(vb.z, vb.w);                 \
      g.u[0] = cvtpk(vc.x, vc.y); g.u[1] = cvtpk(vc.z, vc.w);                 \
      g.u[2] = cvtpk(vd.x, vd.y); g.u[3] = cvtpk(vd.z, vd.w);                 \
      __builtin_amdgcn_s_setprio(1);                                          \
      acc[0][0] = __builtin_amdgcn_mfma_f32_32x32x16_bf16(f.v, bfr[0][kf], acc[0][0], 0, 0, 0); \
      acc[0][1] = __builtin_amdgcn_mfma_f32_32x32x16_bf16(f.v, bfr[1][kf], acc[0][1], 0, 0, 0); \
      acc[1][0] = __builtin_amdgcn_mfma_f32_32x32x16_bf16(g.v, bfr[0][kf], acc[1][0], 0, 0, 0); \
      acc[1][1] = __builtin_amdgcn_mfma_f32_32x32x16_bf16(g.v, bfr[1][kf], acc[1][1], 0, 0, 0); \
      __builtin_amdgcn_s_setprio(0);                                          \
    }                                                                         \
    ++b3; if (b3 >= 3) b3 -= 3;                                               \
  }                                                                           \
  __syncthreads();                                                            \
  float b1v[2];                                                               \
  _Pragma("unroll") for (int nt = 0; nt < 2; ++nt)                            \
    b1v[nt] = b1[wn * 64 + nt * 32 + l31];                                    \
  _Pragma("unroll") for (int mt = 0; mt < 2; ++mt) {                          \
    _Pragma("unroll") for (int nt = 0; nt < 2; ++nt) {                        \
      int col = wn * 64 + nt * 32 + l31;                                      \
      _Pragma("unroll") for (int rg = 0; rg < 16; ++rg) {                     \
        int row = mt * 32 + (rg & 3) + 8 * (rg >> 2) + 4 * lh;                \
        float v = acc[mt][nt][rg] + b1v[nt];                                  \
        v = v > 0.f ? v : 0.f;                                                \
        int j = (col >> 3) ^ (row & 31);                                      \
        *(unsigned short*)(smem + row * 512 + (j << 4) + (col & 7) * 2) =     \
            (unsigned short)cvtpk(v, v);                                      \
      }                                                                       \
    }                                                                         \
  }                                                                           \
  __syncthreads();

#define XSTAGE(b3_, k0)                                         \
  { char* xb_ = smem + (b3_) * XBUF;                            \
    gload16(x + xsrc[0] + (k0), xb_ + xdst[0]);                 \
    gload16(x + xsrc[1] + (k0), xb_ + xdst[1]); }

// ---- gemm1: h = relu(x@W1^T+b1), exported in fragment-ready layout ----
// h chunk idx = rowblk*1024 + kb*32 + rr  (rowblk=row>>5, kb=k>>3, rr=row&31)
__global__ __launch_bounds__(256, 4) void gemm1(
    const float* __restrict__ x,
    const unsigned short* __restrict__ w1f,
    const float* __restrict__ b1,
    unsigned short* __restrict__ hfrag) {
  __shared__ __align__(16) char smem[32768];
  const int tid = threadIdx.x;
  const int lane = tid & 63;
  const int wn = tid >> 6;
  const int l31 = lane & 31;
  const int lh = lane >> 5;
  const int row0 = blockIdx.x * BM;

  L1_PROLOG_AND_LOOP();

  // frag-layout export: 8 passes, 512B-contiguous per 32 lanes
  char* hb = (char*)hfrag;
#pragma unroll
  for (int p = 0; p < 8; ++p) {
    int f = p * 256 + tid;
    int rr = f & 31;
    int j = (f >> 5) & 31;
    int rb = f >> 10;                 // 0..1
    int r = rb * 32 + rr;
    u32x4 v = *(const u32x4*)(smem + r * 512 + ((j ^ rr) << 4));
    *(u32x4*)(hb + ((size_t)((row0 >> 5) + rb) * 1024 + j * 32 + rr) * 16) = v;
  }
}

// ---- gemm2: y = relu(h@W2^T+b2); no LDS, all frag loads coalesced ----
__global__ __launch_bounds__(256, 2) void gemm2(
    const unsigned short* __restrict__ hfrag,
    const unsigned short* __restrict__ w2f,
    const float* __restrict__ b2,
    float* __restrict__ y) {
  const int tid = threadIdx.x;
  const int lane = tid & 63;
  const int w = tid >> 6;
  const int wm2 = w >> 1;      // row half (0..1)
  const int wn2 = w & 1;       // col half (0..1)
  const int l31 = lane & 31;
  const int lh = lane >> 5;
  const int row0 = blockIdx.x * 64;

  const char* ab = (const char*)hfrag +
                   ((size_t)((row0 >> 5) + wm2) * 16384) + l31 * 16 + lh * 512;
  const char* bb = (const char*)w2f + wn2 * 16384 + l31 * 16 + lh * 512;

  bf16x8 A[16], B[16];
#pragma unroll
  for (int m = 0; m < 16; ++m) {
    A[m] = *(const bf16x8*)(ab + m * 1024);   // kb = m*2 + lh
    B[m] = *(const bf16x8*)(bb + m * 1024);
  }

  f32x16 acc;
#pragma unroll
  for (int q = 0; q < 16; ++q) acc[q] = 0.f;
#pragma unroll
  for (int m = 0; m < 16; ++m)
    acc = __builtin_amdgcn_mfma_f32_32x32x16_bf16(A[m], B[m], acc, 0, 0, 0);

  float bias = b2[wn2 * 32 + l31];
#pragma unroll
  for (int rg = 0; rg < 16; ++rg) {
    int row = (rg & 3) + 8 * (rg >> 2) + 4 * lh;
    float v = acc[rg] + bias;
    v = v > 0.f ? v : 0.f;
    y[(size_t)(row0 + wm2 * 32 + row) * NOUT + wn2 * 32 + l31] = v;
  }
}

// ---- fused fallback (R8 + fixed tail + w2f layer 2), if ws too small ----
__global__ __launch_bounds__(256, 4) void livenet_fused(
    const float* __restrict__ x,
    const unsigned short* __restrict__ w1f,
    const float* __restrict__ b1,
    const unsigned short* __restrict__ w2f,
    const float* __restrict__ b2,
    float* __restrict__ y) {
  __shared__ __align__(16) char smem[32768];
  const int tid = threadIdx.x;
  const int lane = tid & 63;
  const int wn = tid >> 6;
  const int l31 = lane & 31;
  const int lh = lane >> 5;
  const int row0 = blockIdx.x * BM;

  L1_PROLOG_AND_LOOP();

  // layer 2 from h-LDS + w2f frags
  const int w = wn;
  f32x16 acc2;
#pragma unroll
  for (int q = 0; q < 16; ++q) acc2[q] = 0.f;
  const int r2 = (w >> 1) * 32;
  const int c2i = w & 1;
  const int arow = r2 + l31;
  const uint32_t arx2 = (uint32_t)(arow & 31);
  const char* bb = (const char*)w2f + c2i * 16384 + l31 * 16 + lh * 512;
#pragma unroll
  for (int kk = 0; kk < 16; ++kk) {
    bf16x8 a2 = *(const bf16x8*)(smem + arow * 512 +
                                 ((((uint32_t)(kk * 2 + lh)) ^ arx2) << 4));
    bf16x8 bw = *(const bf16x8*)(bb + kk * 1024);
    acc2 = __builtin_amdgcn_mfma_f32_32x32x16_bf16(a2, bw, acc2, 0, 0, 0);
  }
  float bias2 = b2[c2i * 32 + l31];
#pragma unroll
  for (int rg = 0; rg < 16; ++rg) {
    int row = r2 + (rg & 3) + 8 * (rg >> 2) + 4 * lh;
    float v = acc2[rg] + bias2;
    v = v > 0.f ? v : 0.f;
    y[(size_t)(row0 + row) * NOUT + c2i * 32 + l31] = v;
  }
}

extern "C" void kernel_launch(void* const* d_in, const int* in_sizes, int n_in,
                              void* d_out, int out_size, void* d_ws, size_t ws_size,
                              hipStream_t stream) {
  const float* x  = (const float*)d_in[0];
  const float* W1 = (const float*)d_in[1];
  const float* b1 = (const float*)d_in[2];
  const float* W2 = (const float*)d_in[3];
  const float* b2 = (const float*)d_in[4];
  float* y = (float*)d_out;

  unsigned short* w1f = (unsigned short*)d_ws;             // 512 KB
  unsigned short* w2f = w1f + (size_t)NMID * NIN;          // 32 KB
  unsigned short* hfrag = w2f + (size_t)NOUT * NMID;       // 32 MB (split path)

  const int batch = in_sizes[0] / NIN;
  const size_t need = ((size_t)NMID * NIN + (size_t)NOUT * NMID +
                       (size_t)batch * NMID) * 2;

  hipLaunchKernelGGL(cvt_weights, dim3(136), dim3(256), 0, stream,
                     W1, W2, w1f, w2f);

  if (ws_size >= need) {
    hipLaunchKernelGGL(gemm1, dim3(batch / BM), dim3(256), 0, stream,
                       x, w1f, b1, hfrag);
    hipLaunchKernelGGL(gemm2, dim3(batch / 64), dim3(256), 0, stream,
                       hfrag, w2f, b2, y);
  } else {
    hipLaunchKernelGGL(livenet_fused, dim3(batch / BM), dim3(256), 0, stream,
                       x, w1f, b1, w2f, b2, y);
  }
}